// Round 4
// baseline (1134.853 us; speedup 1.0000x reference)
//
#include <hip/hip_runtime.h>
#include <stdint.h>

#define NB3 8112
#define NB4 2028
#define NB5 507
#define NTOT 10647           // 8112 + 2028 + 507
#define NBATCH 4
#define NCLS 20
#define NW32 333             // ceil(10647 / 32)
#define NW64 167             // ceil(10647 / 64)
#define NSG 84               // ceil(NW64 / 2) super-groups of 128 boxes
#define LDS_CAP 9984         // boxes staged in LDS (fallback kernel)
#define CONF_THR_F 0.1f
#define IOU_THR_F 0.45f

typedef unsigned long long u64;

// ---------------------------------------------------------------------------
// Kernel A: per-box score / class argmax / sort key
// ---------------------------------------------------------------------------
__global__ void prep_kernel(const float* __restrict__ p3b, const float* __restrict__ p3c, const float* __restrict__ p3k,
                            const float* __restrict__ p4b, const float* __restrict__ p4c, const float* __restrict__ p4k,
                            const float* __restrict__ p5b, const float* __restrict__ p5c, const float* __restrict__ p5k,
                            uint64_t* __restrict__ keys, float4* __restrict__ boxes_cat,
                            float* __restrict__ score, int* __restrict__ clsidx, uint32_t* __restrict__ svout)
{
#pragma clang fp contract(off)
    int idx = blockIdx.x * 256 + threadIdx.x;
    if (idx >= NBATCH * NTOT) return;
    int b = idx / NTOT;
    int i = idx - b * NTOT;

    const float* bx; const float* cf; const float* cl; int n, off;
    if (i < NB3)            { bx = p3b; cf = p3c; cl = p3k; n = NB3; off = i; }
    else if (i < NB3 + NB4) { bx = p4b; cf = p4c; cl = p4k; n = NB4; off = i - NB3; }
    else                    { bx = p5b; cf = p5c; cl = p5k; n = NB5; off = i - NB3 - NB4; }

    size_t e = (size_t)b * n + off;
    float4 box = *(const float4*)(bx + e * 4);
    float conf = cf[e];
    const float* c = cl + e * NCLS;
    float m = c[0]; int mi = 0;
    #pragma unroll
    for (int k = 1; k < NCLS; ++k) { float v = c[k]; if (v > m) { m = v; mi = k; } }

    bool valid = conf > CONF_THR_F;
    float s = valid ? conf * m : 0.0f;           // exact: single f32 mul, no fma
    uint32_t sb = __float_as_uint(s);            // s >= 0 -> bits monotonic
    keys[idx]      = ((uint64_t)sb << 32) | (uint32_t)(0xFFFFFFFFu - (uint32_t)i);
    boxes_cat[idx] = box;
    score[idx]     = s;
    clsidx[idx]    = mi;
    svout[idx]     = valid ? 1u : 0u;
}

// ---------------------------------------------------------------------------
// Kernel B: stable descending rank sort (rank = #keys strictly greater),
// scatter sorted arrays. No atomics (valid bitmap built inside resolve).
// ---------------------------------------------------------------------------
__global__ void rank_kernel(const uint64_t* __restrict__ keys,
                            const float4* __restrict__ boxes_cat,
                            const float* __restrict__ score,
                            const int* __restrict__ clsidx,
                            const uint32_t* __restrict__ sv,
                            float4* __restrict__ sboxes, float* __restrict__ sscore,
                            int* __restrict__ scls, uint32_t* __restrict__ ssv)
{
    int b = blockIdx.y;
    int i = blockIdx.x * 256 + threadIdx.x;
    const uint64_t* kb = keys + (size_t)b * NTOT;
    uint64_t mykey = (i < NTOT) ? kb[i] : 0ull;

    __shared__ uint64_t tile[256];
    int rank = 0;
    for (int t0 = 0; t0 < NTOT; t0 += 256) {
        int j = t0 + threadIdx.x;
        tile[threadIdx.x] = (j < NTOT) ? kb[j] : 0ull;   // 0 never > any real key
        __syncthreads();
        #pragma unroll 8
        for (int t = 0; t < 256; ++t) rank += (tile[t] > mykey) ? 1 : 0;
        __syncthreads();
    }

    if (i < NTOT) {
        size_t src = (size_t)b * NTOT + i;
        size_t dst = (size_t)b * NTOT + rank;
        sboxes[dst] = boxes_cat[src];
        sscore[dst] = score[src];
        scls[dst]   = clsidx[src];
        ssv[dst]    = sv[src];
    }
}

// ---------------------------------------------------------------------------
// Kernel C1 (fast path): build suppression bit-matrix + compact diag2 blocks.
// mask[(b*NTOT + i)*NW64 + c] : bit k set iff IoU(i, c*64+k)>thr and col>i.
// Only upper-triangle chunks (c >= r) are written.
// diag2[((b*NSG + s)*128 + rowin)*2 + w] = mask word (2s+w) of row s*128+rowin
// (the 128x128 diagonal block of super-group s, compact layout for resolve).
// ---------------------------------------------------------------------------
__global__ void __launch_bounds__(256) mask_build(const float4* __restrict__ sboxes,
                                                  u64* __restrict__ mask,
                                                  u64* __restrict__ diag2)
{
#pragma clang fp contract(off)
    int c = blockIdx.y;
    if (c < blockIdx.x * 4) return;              // whole block below diagonal
    int b = blockIdx.z;
    int sub = threadIdx.x >> 6;
    int lane = threadIdx.x & 63;
    int r = blockIdx.x * 4 + sub;

    __shared__ float4 cb[64];
    __shared__ float  ca[64];
    if (threadIdx.x < 64) {
        int j = c * 64 + threadIdx.x;
        float4 bj = sboxes[(size_t)b * NTOT + (j < NTOT ? j : NTOT - 1)];
        cb[threadIdx.x] = bj;
        ca[threadIdx.x] = (bj.z - bj.x) * (bj.w - bj.y);
    }
    __syncthreads();

    if (r >= NW64 || c < r) return;              // wave below diagonal / OOB
    int i = r * 64 + lane;
    float4 bi = sboxes[(size_t)b * NTOT + (i < NTOT ? i : NTOT - 1)];
    float ax1 = bi.x, ay1 = bi.y, ax2 = bi.z, ay2 = bi.w;
    float area_i = (ax2 - ax1) * (ay2 - ay1);

    u64 m = 0;
    #pragma unroll 8
    for (int k = 0; k < 64; ++k) {
        float4 bj = cb[k];
        float xx1 = fmaxf(bj.x, ax1);
        float yy1 = fmaxf(bj.y, ay1);
        float xx2 = fminf(bj.z, ax2);
        float yy2 = fminf(bj.w, ay2);
        float w = fmaxf(xx2 - xx1, 0.0f);
        float h = fmaxf(yy2 - yy1, 0.0f);
        float inter = w * h;
        float iou = inter / ((area_i + ca[k]) - inter);   // matches ref op order
        bool set = (iou > IOU_THR_F) && (c > r || k > lane) && (c * 64 + k < NTOT);
        m |= (u64)set << k;
    }
    if (i < NTOT) {
        mask[((size_t)b * NTOT + i) * NW64 + c] = m;
        if ((c >> 1) == (r >> 1))
            diag2[(((size_t)b * NSG + (r >> 1)) * 128 + ((r & 1) << 6) + lane) * 2 + (c & 1)] = m;
    }
}

// ---------------------------------------------------------------------------
// Kernel C2 (fast path): greedy resolve, column-parallel.
// One block of 192 threads (3 waves) per image. Thread t owns removed-word t.
// Super-groups of 128 boxes: per sg, intra-sg greedy decided via v_readlane
// on register-resident diag2 (prefetched), then ONE batched load round-trip
// ORs all kept rows into each thread's word.
// ---------------------------------------------------------------------------
__device__ __forceinline__ u64 rl64(u64 x, int l) {
    int ll = __builtin_amdgcn_readfirstlane(l);
    uint32_t lo = __builtin_amdgcn_readlane((uint32_t)x, ll);
    uint32_t hi = __builtin_amdgcn_readlane((uint32_t)(x >> 32), ll);
    return ((u64)hi << 32) | lo;
}
__device__ __forceinline__ u64 dsel(int f, u64 d0, u64 d1, u64 d2, u64 d3) {
    int sl = f >> 6;
    u64 x = (sl == 0) ? d0 : (sl == 1) ? d1 : (sl == 2) ? d2 : d3;
    return rl64(x, f & 63);
}

__global__ void __launch_bounds__(192) resolve_kernel(const u64* __restrict__ mask,
                                                      const u64* __restrict__ diag2,
                                                      const uint32_t* __restrict__ ssv,
                                                      u64* __restrict__ rem_out)
{
    int b = blockIdx.x;
    int t = threadIdx.x;
    int lane = t & 63;
    int wv = t >> 6;
    const u64* M = mask + (size_t)b * NTOT * NW64;

    __shared__ u64 ldsV[192];
    __shared__ u64 ldsCur[4];

    // build valid bitmap via per-wave ballot (coalesced, no atomics)
    ldsV[t] = 0;
    __syncthreads();
    const uint32_t* sp = ssv + (size_t)b * NTOT;
    for (int w = wv; w < NW64; w += 3) {
        int j = w * 64 + lane;
        uint32_t x = (j < NTOT) ? sp[j] : 0u;
        u64 bal = __ballot(x != 0u);
        if (lane == 0) ldsV[w] = bal;
    }
    __syncthreads();
    u64 v0 = ldsV[lane], v1 = ldsV[64 + lane], v2 = ldsV[128 + lane];

    // preload diag2 for sg 0 (flat layout: 256 u64 per sg; lane l holds
    // flat indices l, 64+l, 128+l, 192+l; flat = rowin*2 + word)
    const u64* db0 = diag2 + (size_t)b * NSG * 256;
    u64 d0 = db0[lane], d1 = db0[64 + lane], d2 = db0[128 + lane], d3 = db0[192 + lane];

    u64 rem = 0;

    for (int s = 0; s < NSG; ++s) {
        // prefetch next sg's diag block (hidden under barrier+chain+loads)
        int sn = (s + 1 < NSG) ? s + 1 : s;
        const u64* dbn = diag2 + ((size_t)b * NSG + sn) * 256;
        u64 p0 = dbn[lane], p1 = dbn[64 + lane], p2 = dbn[128 + lane], p3 = dbn[192 + lane];

        int w0 = 2 * s, w1 = 2 * s + 1;
        int buf = (s & 1) * 2;
        if (t == w0) ldsCur[buf] = rem;
        if (t == w1) ldsCur[buf + 1] = rem;
        __syncthreads();
        u64 cur0 = ldsCur[buf], cur1 = ldsCur[buf + 1];

        u64 V0 = rl64((w0 < 64) ? v0 : (w0 < 128) ? v1 : v2, w0 & 63);
        u64 V1 = rl64((w1 < 64) ? v0 : (w1 < 128) ? v1 : v2, w1 & 63);
        u64 alive0 = V0 & ~cur0;
        u64 alive1 = V1 & ~cur1;

        // intra-sg greedy chain: ascending index, readlane on diag regs
        u64 pend0 = alive0, pend1 = alive1, kept0 = 0, kept1 = 0;
        while (pend0 | pend1) {
            bool inw0 = (pend0 != 0);
            u64 pw = inw0 ? pend0 : pend1;
            int i = __ffsll(pw) - 1;
            int fr = ((inw0 ? i : 64 + i) << 1);
            u64 dw1 = dsel(fr + 1, d0, d1, d2, d3);   // row's word (2s+1)
            if (inw0) {
                u64 dw0 = dsel(fr, d0, d1, d2, d3);   // row's word (2s)
                kept0 |= 1ull << i;
                pend0 &= ~(dw0 | (1ull << i));
                pend1 &= ~dw1;
            } else {
                kept1 |= 1ull << i;
                pend1 &= ~(dw1 | (1ull << i));
            }
        }

        // finalize owned words (intra-sg suppression = alive & ~kept)
        if (t == w0) { rem = cur0 | (alive0 & ~kept0); rem_out[(size_t)b * NW64 + t] = rem; }
        if (t == w1 && t < NW64) { rem = cur1 | (alive1 & ~kept1); rem_out[(size_t)b * NW64 + t] = rem; }

        // batched row-OR: each participating thread loads ONE word per kept row
        if (t >= w0 + 2 && t < NW64 && (kept0 | kept1)) {
            u64 k0 = kept0, k1 = kept1;
            int rowbase = s * 128;
            u64 acc = rem;
            while (k0 | k1) {
                uint32_t ro[16]; u64 sm[16];
                uint32_t last = (uint32_t)rowbase * (uint32_t)NW64;
                #pragma unroll
                for (int q = 0; q < 16; ++q) {
                    bool has = (k0 | k1) != 0;
                    int idx;
                    if (k0)      { idx = __ffsll(k0) - 1;        k0 &= k0 - 1; }
                    else if (k1) { idx = 64 + (__ffsll(k1) - 1); k1 &= k1 - 1; }
                    else         { idx = 0; }
                    uint32_t r = has ? ((uint32_t)(rowbase + idx) * (uint32_t)NW64) : last;
                    ro[q] = r; last = r;
                    sm[q] = has ? ~0ull : 0ull;
                }
                u64 vals[16];
                #pragma unroll
                for (int q = 0; q < 16; ++q) vals[q] = M[(size_t)ro[q] + t];
                #pragma unroll
                for (int q = 0; q < 16; ++q) acc |= vals[q] & sm[q];
            }
            rem = acc;
        }

        d0 = p0; d1 = p1; d2 = p2; d3 = p3;
    }
}

// ---------------------------------------------------------------------------
// Fallback (small ws): single-block NMS (safety net, nv = NTOT).
// ---------------------------------------------------------------------------
extern __shared__ unsigned char nms_smem[];

__global__ void __launch_bounds__(1024) nms_kernel(const float4* __restrict__ sboxes,
                                                   const uint32_t* __restrict__ ssv,
                                                   uint32_t* __restrict__ supp_out)
{
#pragma clang fp contract(off)
    int b = blockIdx.x;
    float4*   lbox = (float4*)nms_smem;
    uint32_t* supp = (uint32_t*)(nms_smem + (size_t)LDS_CAP * 16);
    uint32_t* svb  = supp + NW32;

    const int nv = NTOT;
    const float4* gb = sboxes + (size_t)b * NTOT;
    const uint32_t* gv = ssv + (size_t)b * NTOT;

    for (int t = threadIdx.x; t < NW32; t += 1024) { supp[t] = 0u; svb[t] = 0u; }
    __syncthreads();
    for (int t = threadIdx.x; t < nv; t += 1024) {
        if (t < LDS_CAP) lbox[t] = gb[t];
        if (gv[t]) atomicOr(&svb[t >> 5], 1u << (t & 31));
    }
    __syncthreads();

    for (int i = 0; i < nv; ++i) {
        uint32_t sw = supp[i >> 5];
        if ((sw >> (i & 31)) & 1u) continue;
        uint32_t vw = svb[i >> 5];
        if (!((vw >> (i & 31)) & 1u)) continue;

        float4 bi = (i < LDS_CAP) ? lbox[i] : gb[i];
        float ax1 = bi.x, ay1 = bi.y, ax2 = bi.z, ay2 = bi.w;
        float area_i = (ax2 - ax1) * (ay2 - ay1);

        for (int j = i + 1 + (int)threadIdx.x; j < nv; j += 1024) {
            float4 bj = (j < LDS_CAP) ? lbox[j] : gb[j];
            float xx1 = fmaxf(bj.x, ax1);
            float yy1 = fmaxf(bj.y, ay1);
            float xx2 = fminf(bj.z, ax2);
            float yy2 = fminf(bj.w, ay2);
            float w = fmaxf(xx2 - xx1, 0.0f);
            float h = fmaxf(yy2 - yy1, 0.0f);
            float inter  = w * h;
            float area_j = (bj.z - bj.x) * (bj.w - bj.y);
            float iou = inter / ((area_i + area_j) - inter);
            if (iou > IOU_THR_F) atomicOr(&supp[j >> 5], 1u << (j & 31));
        }
        __syncthreads();
    }

    __syncthreads();
    for (int t = threadIdx.x; t < NW32; t += 1024)
        supp_out[(size_t)b * (2 * NW64) + t] = supp[t];
}

// ---------------------------------------------------------------------------
// Kernel D: assemble outputs: dets [B,N,6] then keep [B,N] (as 0/1 floats)
// ---------------------------------------------------------------------------
__global__ void out_kernel(const float4* __restrict__ sboxes, const float* __restrict__ sscore,
                           const int* __restrict__ scls, const uint32_t* __restrict__ ssv,
                           const u64* __restrict__ rem, float* __restrict__ out)
{
    int idx = blockIdx.x * 256 + threadIdx.x;
    if (idx >= NBATCH * NTOT) return;
    int b = idx / NTOT;
    int p = idx - b * NTOT;

    float4 box = sboxes[idx];
    u64 rw = rem[(size_t)b * NW64 + (p >> 6)];
    bool keep = (ssv[idx] != 0u) && !((rw >> (p & 63)) & 1ull);
    float sc = keep ? sscore[idx] : 0.0f;

    float* d = out + (size_t)idx * 6;
    d[0] = box.x; d[1] = box.y; d[2] = box.z; d[3] = box.w;
    d[4] = sc;    d[5] = (float)scls[idx];
    out[(size_t)NBATCH * NTOT * 6 + idx] = keep ? 1.0f : 0.0f;
}

// ---------------------------------------------------------------------------
extern "C" void kernel_launch(void* const* d_in, const int* in_sizes, int n_in,
                              void* d_out, int out_size, void* d_ws, size_t ws_size,
                              hipStream_t stream)
{
    const float* p3b = (const float*)d_in[0];
    const float* p3c = (const float*)d_in[1];
    const float* p3k = (const float*)d_in[2];
    const float* p4b = (const float*)d_in[3];
    const float* p4c = (const float*)d_in[4];
    const float* p4k = (const float*)d_in[5];
    const float* p5b = (const float*)d_in[6];
    const float* p5c = (const float*)d_in[7];
    const float* p5k = (const float*)d_in[8];
    float* out = (float*)d_out;

    // workspace carve-up (256B aligned slabs)
    char* ws = (char*)d_ws;
    size_t off = 0;
    auto alloc = [&](size_t bytes) { size_t o = off; off += (bytes + 255) & ~(size_t)255; return o; };
    const size_t BN = (size_t)NBATCH * NTOT;
    uint64_t* keys      = (uint64_t*)(ws + alloc(BN * 8));
    float4*   boxes_cat = (float4*)  (ws + alloc(BN * 16));
    float*    score     = (float*)   (ws + alloc(BN * 4));
    int*      clsidx    = (int*)     (ws + alloc(BN * 4));
    uint32_t* sv        = (uint32_t*)(ws + alloc(BN * 4));
    float4*   sboxes    = (float4*)  (ws + alloc(BN * 16));
    float*    sscore    = (float*)   (ws + alloc(BN * 4));
    int*      scls      = (int*)     (ws + alloc(BN * 4));
    uint32_t* ssv       = (uint32_t*)(ws + alloc(BN * 4));
    u64*      rem64     = (u64*)     (ws + alloc((size_t)NBATCH * NW64 * 8));
    u64*      diag2     = (u64*)     (ws + alloc((size_t)NBATCH * NSG * 256 * 8));
    u64*      mask      = (u64*)     (ws + alloc((size_t)NBATCH * NTOT * NW64 * 8));
    bool fast = (off <= ws_size);

    int nblk = (int)((BN + 255) / 256);
    prep_kernel<<<nblk, 256, 0, stream>>>(p3b, p3c, p3k, p4b, p4c, p4k, p5b, p5c, p5k,
                                          keys, boxes_cat, score, clsidx, sv);

    dim3 rgrid((NTOT + 255) / 256, NBATCH);
    rank_kernel<<<rgrid, 256, 0, stream>>>(keys, boxes_cat, score, clsidx, sv,
                                           sboxes, sscore, scls, ssv);

    if (fast) {
        dim3 mgrid((NW64 + 3) / 4, NW64, NBATCH);
        mask_build<<<mgrid, 256, 0, stream>>>(sboxes, mask, diag2);
        resolve_kernel<<<NBATCH, 192, 0, stream>>>(mask, diag2, ssv, rem64);
    } else {
        size_t smem = (size_t)LDS_CAP * 16 + (size_t)NW32 * 4 * 2;
        smem = (smem + 15) & ~(size_t)15;
        hipFuncSetAttribute((const void*)nms_kernel, hipFuncAttributeMaxDynamicSharedMemorySize, (int)smem);
        nms_kernel<<<NBATCH, 1024, smem, stream>>>(sboxes, ssv, (uint32_t*)rem64);
    }

    out_kernel<<<nblk, 256, 0, stream>>>(sboxes, sscore, scls, ssv, rem64, out);
}